// Round 5
// baseline (1676.031 us; speedup 1.0000x reference)
//
#include <hip/hip_runtime.h>
#include <hip/hip_bf16.h>
#include <cstdint>

typedef __attribute__((ext_vector_type(8))) short u16x8;
typedef _Float16 f16_t;
typedef __attribute__((ext_vector_type(8))) f16_t f16x8;
typedef __attribute__((ext_vector_type(4))) float f32x4;

#define L_TOT 4608
#define L_TXT 512
#define L_IMG 4096
#define NH 24
#define HD 128
#define DMODEL 3072
#define NQKV 9216
#define LOG2E 1.44269504088896340736f
#define S_SHIFT 32.0f

__device__ __forceinline__ ushort f2h(float f) {
  union { f16_t h; ushort u; } c; c.h = (f16_t)f; return c.u;
}
__device__ __forceinline__ float h2f(ushort u) {
  union { ushort u; f16_t h; } c; c.u = u; return (float)c.h;
}
__device__ __forceinline__ void gload16(const ushort* g, ushort* l) {
  __builtin_amdgcn_global_load_lds((const __attribute__((address_space(1))) void*)g,
                                   (__attribute__((address_space(3))) void*)l, 16, 0, 0);
}

// ---------------- GEMM: C[M][N] = A[M][K] @ B, 128x128 tile, BK=32, 4 waves -----------
// ASRC: 0 = A fp16 [M][K] via global_load_lds ; 1 = A f32 [M][K] via reg-stage + cvt
// BSRC: 0 = B fp16 [N][K] via global_load_lds ; 1 = B fp16 [K][N] reg transpose ;
//       2 = B f32  [K][N] reg transpose + cvt
// MODE: 0 = qkv scatter fp16 into merged Q/K/V [l][3072] (l = l_off + m, col = n%3072)
//       1 = f32 out + f32 bias ; 2 = plain fp16 out ; 3 = fp16 out, minus S_SHIFT
template <int MODE, int ASRC, int BSRC>
__global__ void gemm(const void* __restrict__ Av, int lda,
                     const void* __restrict__ Bv, int ldb,
                     int M, int N, int K,
                     void* __restrict__ out0, ushort* __restrict__ out1,
                     ushort* __restrict__ out2, const float* __restrict__ bias,
                     int l_off) {
  __shared__ __align__(16) ushort Alds[128 * 32];
  __shared__ __align__(16) ushort Blds[128 * 32];
  const int m0 = blockIdx.x << 7, n0 = blockIdx.y << 7;
  const int tid = threadIdx.x, wave = tid >> 6, lane = tid & 63;
  const int wr = wave >> 1, wc = wave & 1;
  const int lrow = lane & 15, lk8 = (lane >> 4) << 3;
  f32x4 acc[4][4];
#pragma unroll
  for (int a = 0; a < 4; ++a)
#pragma unroll
    for (int b = 0; b < 4; ++b) acc[a][b] = (f32x4){0.f, 0.f, 0.f, 0.f};
  const int nk = K >> 5;

  // A staging addresses
  const ushort* Ap = nullptr;  const float* Apf = nullptr;
  int arow_f = 0, ao_f = 0;
  if (ASRC == 0) {
    Ap = (const ushort*)Av + (size_t)(m0 + (tid >> 2)) * lda + ((tid & 3) << 3);
  } else {
    arow_f = tid >> 1; ao_f = (tid & 1) << 4;
    Apf = (const float*)Av + (size_t)(m0 + arow_f) * lda + ao_f;
  }
  // B staging addresses
  const ushort* Bp = nullptr; const ushort* Bq = nullptr; const float* Bqf = nullptr;
  int bk = 0, bc = 0;
  if (BSRC == 0) {
    Bp = (const ushort*)Bv + (size_t)(n0 + (tid >> 2)) * ldb + ((tid & 3) << 3);
  } else {
    bk = tid >> 3; bc = (tid & 7) << 4;
    if (BSRC == 1) Bq  = (const ushort*)Bv + (size_t)bk * ldb + n0 + bc;
    else           Bqf = (const float*)Bv  + (size_t)bk * ldb + n0 + bc;
  }

  for (int ks = 0; ks < nk; ++ks) {
    f32x4 a4[4];
    u16x8 bs0, bs1;
    f32x4 b4[4];
    if (ASRC == 1) {
      const float* as = Apf + (ks << 5);
      a4[0] = *(const f32x4*)as;       a4[1] = *(const f32x4*)(as + 4);
      a4[2] = *(const f32x4*)(as + 8); a4[3] = *(const f32x4*)(as + 12);
    }
    if (BSRC == 1) {
      const ushort* bsrc = Bq + (size_t)(ks << 5) * ldb;
      bs0 = *(const u16x8*)bsrc;
      bs1 = *(const u16x8*)(bsrc + 8);
    } else if (BSRC == 2) {
      const float* bsrc = Bqf + (size_t)(ks << 5) * ldb;
      b4[0] = *(const f32x4*)bsrc;       b4[1] = *(const f32x4*)(bsrc + 4);
      b4[2] = *(const f32x4*)(bsrc + 8); b4[3] = *(const f32x4*)(bsrc + 12);
    }
    __syncthreads();  // previous iteration's LDS readers done
    if (ASRC == 0) {
      const ushort* a0 = Ap + (ks << 5);
      gload16(a0, &Alds[wave << 9]);
      gload16(a0 + (size_t)64 * lda, &Alds[2048 + (wave << 9)]);
    } else {
      alignas(16) ushort ac[16];
      const float* af_ = (const float*)a4;
#pragma unroll
      for (int i = 0; i < 16; ++i) ac[i] = f2h(af_[i]);
      *(u16x8*)&Alds[arow_f * 32 + ao_f]     = *(const u16x8*)ac;
      *(u16x8*)&Alds[arow_f * 32 + ao_f + 8] = *(const u16x8*)(ac + 8);
    }
    if (BSRC == 0) {
      const ushort* b0 = Bp + (ks << 5);
      gload16(b0, &Blds[wave << 9]);
      gload16(b0 + (size_t)64 * ldb, &Blds[2048 + (wave << 9)]);
    } else if (BSRC == 1) {
#pragma unroll
      for (int i = 0; i < 8; ++i) {
        Blds[(bc + i) * 32 + bk]     = ((const ushort*)&bs0)[i];
        Blds[(bc + 8 + i) * 32 + bk] = ((const ushort*)&bs1)[i];
      }
    } else {
      const float* bf_ = (const float*)b4;
#pragma unroll
      for (int i = 0; i < 16; ++i) Blds[(bc + i) * 32 + bk] = f2h(bf_[i]);
    }
    __syncthreads();  // tiles ready
    f16x8 af[4], bfr[4];
#pragma unroll
    for (int mt = 0; mt < 4; ++mt)
      af[mt] = *(const f16x8*)&Alds[((wr << 6) + (mt << 4) + lrow) * 32 + lk8];
#pragma unroll
    for (int nt = 0; nt < 4; ++nt)
      bfr[nt] = *(const f16x8*)&Blds[((wc << 6) + (nt << 4) + lrow) * 32 + lk8];
#pragma unroll
    for (int mt = 0; mt < 4; ++mt)
#pragma unroll
      for (int nt = 0; nt < 4; ++nt)
        acc[mt][nt] = __builtin_amdgcn_mfma_f32_16x16x32_f16(af[mt], bfr[nt], acc[mt][nt], 0, 0, 0);
  }
  const int rb = (lane >> 4) << 2;
  if (MODE == 0) {
    const int which = n0 / DMODEL;
    const int col0 = n0 - which * DMODEL;
    ushort* dst = (which == 0) ? (ushort*)out0 : (which == 1) ? out1 : out2;
#pragma unroll
    for (int mt = 0; mt < 4; ++mt)
#pragma unroll
      for (int j = 0; j < 4; ++j) {
        const int l = l_off + m0 + (wr << 6) + (mt << 4) + rb + j;
        const size_t rbase = (size_t)l * DMODEL + col0 + (wc << 6) + lrow;
#pragma unroll
        for (int nt = 0; nt < 4; ++nt) dst[rbase + (nt << 4)] = f2h(acc[mt][nt][j]);
      }
  } else if (MODE == 1) {
    float* outf = (float*)out0;
    float bv[4];
#pragma unroll
    for (int nt = 0; nt < 4; ++nt) bv[nt] = bias[n0 + (wc << 6) + (nt << 4) + lrow];
#pragma unroll
    for (int mt = 0; mt < 4; ++mt)
#pragma unroll
      for (int j = 0; j < 4; ++j) {
        const int r = m0 + (wr << 6) + (mt << 4) + rb + j;
        const size_t rbase = (size_t)r * N + n0 + (wc << 6) + lrow;
#pragma unroll
        for (int nt = 0; nt < 4; ++nt) outf[rbase + (nt << 4)] = acc[mt][nt][j] + bv[nt];
      }
  } else {
    ushort* outb = (ushort*)out0;
    const float sh = (MODE == 3) ? S_SHIFT : 0.0f;
#pragma unroll
    for (int mt = 0; mt < 4; ++mt)
#pragma unroll
      for (int j = 0; j < 4; ++j) {
        const int r = m0 + (wr << 6) + (mt << 4) + rb + j;
        const size_t rbase = (size_t)r * N + n0 + (wc << 6) + lrow;
#pragma unroll
        for (int nt = 0; nt < 4; ++nt) outb[rbase + (nt << 4)] = f2h(acc[mt][nt][j] - sh);
      }
  }
}

// ---------------- fused RMSNorm + RoPE on merged Q,K [l][3072] fp16; f32 params --------
__global__ void norm_rope(ushort* __restrict__ Q, ushort* __restrict__ Kg,
                          const float* __restrict__ rope,
                          const float* __restrict__ qn, const float* __restrict__ kn,
                          const float* __restrict__ eqn, const float* __restrict__ ekn) {
  const int idx = (blockIdx.x << 2) + (threadIdx.x >> 6);  // (l*24 + h)
  const int lane = threadIdx.x & 63;
  const int h = idx % NH, l = idx / NH;
  const float* qsc = (l < L_TXT) ? eqn : qn;
  const float* ksc = (l < L_TXT) ? ekn : kn;
  const size_t base = (size_t)l * DMODEL + h * HD + (lane << 1);
  const f32x4 fcv = *(const f32x4*)(rope + ((size_t)l * 64 + lane) * 4);
  const float fa = fcv[0], fb = fcv[1], fc = fcv[2], fd = fcv[3];
  const float s0 = qsc[lane << 1], s1 = qsc[(lane << 1) + 1];
  const float t0 = ksc[lane << 1], t1 = ksc[(lane << 1) + 1];
  {
    const uint32_t qv = *(const uint32_t*)&Q[base];
    float x0 = h2f((ushort)(qv & 0xffff)), x1 = h2f((ushort)(qv >> 16));
    float ss = x0 * x0 + x1 * x1;
#pragma unroll
    for (int m = 1; m < 64; m <<= 1) ss += __shfl_xor(ss, m);
    const float r = rsqrtf(ss * (1.0f / 128.0f) + 1e-6f);
    x0 *= r * s0;
    x1 *= r * s1;
    const float o0 = (fa * x0 + fb * x1) * 0.08838834764831845f;
    const float o1 = (fc * x0 + fd * x1) * 0.08838834764831845f;
    *(uint32_t*)&Q[base] = (uint32_t)f2h(o0) | ((uint32_t)f2h(o1) << 16);
  }
  {
    const uint32_t kv = *(const uint32_t*)&Kg[base];
    float x0 = h2f((ushort)(kv & 0xffff)), x1 = h2f((ushort)(kv >> 16));
    float ss = x0 * x0 + x1 * x1;
#pragma unroll
    for (int m = 1; m < 64; m <<= 1) ss += __shfl_xor(ss, m);
    const float r = rsqrtf(ss * (1.0f / 128.0f) + 1e-6f);
    x0 *= r * t0;
    x1 *= r * t1;
    const float o0 = fa * x0 + fb * x1;
    const float o1 = fc * x0 + fd * x1;
    *(uint32_t*)&Kg[base] = (uint32_t)f2h(o0) | ((uint32_t)f2h(o1) << 16);
  }
}

// ---------------- row softmax in-place on fp16 S[4608][4608] ---------------------------
__global__ void softmax_rows(ushort* __restrict__ S) {
  const int r = blockIdx.x, tid = threadIdx.x;
  ushort* Sr = S + (size_t)r * L_TOT;
  float v[18];
  float m = -3.0e38f;
#pragma unroll
  for (int j = 0; j < 18; ++j) { v[j] = h2f(Sr[tid + (j << 8)]); m = fmaxf(m, v[j]); }
#pragma unroll
  for (int o = 1; o < 64; o <<= 1) m = fmaxf(m, __shfl_xor(m, o));
  __shared__ float redm[4], reds[4];
  const int wave = tid >> 6, lane = tid & 63;
  if (lane == 0) redm[wave] = m;
  __syncthreads();
  m = fmaxf(fmaxf(redm[0], redm[1]), fmaxf(redm[2], redm[3]));
  float s = 0.f;
#pragma unroll
  for (int j = 0; j < 18; ++j) { v[j] = exp2f((v[j] - m) * LOG2E); s += v[j]; }
#pragma unroll
  for (int o = 1; o < 64; o <<= 1) s += __shfl_xor(s, o);
  if (lane == 0) reds[wave] = s;
  __syncthreads();
  const float inv = 1.0f / (reds[0] + reds[1] + reds[2] + reds[3]);
#pragma unroll
  for (int j = 0; j < 18; ++j) Sr[tid + (j << 8)] = f2h(v[j] * inv);
}

extern "C" void kernel_launch(void* const* d_in, const int* in_sizes, int n_in,
                              void* d_out, int out_size, void* d_ws, size_t ws_size,
                              hipStream_t stream) {
  (void)in_sizes; (void)n_in; (void)out_size; (void)ws_size;
  const float* hidden  = (const float*)d_in[0];
  const float* enc     = (const float*)d_in[1];
  const float* rope    = (const float*)d_in[2];
  const float* W_iqkv  = (const float*)d_in[3];
  const float* W_eqkv  = (const float*)d_in[4];
  const float* W_iproj = (const float*)d_in[5];
  const float* b_iproj = (const float*)d_in[6];
  const float* W_eproj = (const float*)d_in[7];
  const float* b_eproj = (const float*)d_in[8];
  const float* qn  = (const float*)d_in[9];
  const float* kn  = (const float*)d_in[10];
  const float* eqn = (const float*)d_in[11];
  const float* ekn = (const float*)d_in[12];
  float* out = (float*)d_out;

  // workspace (ushort units): S fp16 (42.5 MB) + QR/KR/VR fp16 (28.3 MB each) = 127 MB
  const size_t SZ_S  = (size_t)L_TOT * L_TOT;
  const size_t SZ_LD = (size_t)L_TOT * DMODEL;
  ushort* S  = (ushort*)d_ws;
  ushort* QR = S + SZ_S;
  ushort* KR = QR + SZ_LD;
  ushort* VR = KR + SZ_LD;
  ushort* AO = QR;  // attention output aliases QR (QR dead after S GEMM)

  dim3 blk(256);
  // QKV projections: A f32 [l][3072] @ W f32 [3072][9216] -> fp16 Q/K/V [l][3072]
  gemm<0, 1, 2><<<dim3(L_IMG / 128, NQKV / 128), blk, 0, stream>>>(
      hidden, DMODEL, W_iqkv, NQKV, L_IMG, NQKV, DMODEL, QR, KR, VR, nullptr, L_TXT);
  gemm<0, 1, 2><<<dim3(L_TXT / 128, NQKV / 128), blk, 0, stream>>>(
      enc, DMODEL, W_eqkv, NQKV, L_TXT, NQKV, DMODEL, QR, KR, VR, nullptr, 0);
  // per-head RMSNorm + RoPE (attn scale folded into Q)
  norm_rope<<<dim3(L_TOT * NH / 4), blk, 0, stream>>>(QR, KR, rope, qn, kn, eqn, ekn);
  // S = Q K^T - 32 (fp16), contraction over merged 3072; K stored [N][K] -> BSRC=0
  gemm<3, 0, 0><<<dim3(L_TOT / 128, L_TOT / 128), blk, 0, stream>>>(
      QR, DMODEL, KR, DMODEL, L_TOT, L_TOT, DMODEL, S, nullptr, nullptr, nullptr, 0);
  // row softmax in place
  softmax_rows<<<dim3(L_TOT), blk, 0, stream>>>(S);
  // AO = P @ V ; V fp16 [K=l][N=3072] -> BSRC=1
  gemm<2, 0, 1><<<dim3(L_TOT / 128, DMODEL / 128), blk, 0, stream>>>(
      S, L_TOT, VR, DMODEL, L_TOT, DMODEL, L_TOT, AO, nullptr, nullptr, nullptr, 0);
  // output projections: A fp16 @ W f32 [3072][3072] -> f32 out + bias
  gemm<1, 0, 2><<<dim3(L_IMG / 128, DMODEL / 128), blk, 0, stream>>>(
      AO + (size_t)L_TXT * DMODEL, DMODEL, W_iproj, DMODEL, L_IMG, DMODEL, DMODEL,
      out, nullptr, nullptr, b_iproj, 0);
  gemm<1, 0, 2><<<dim3(L_TXT / 128, DMODEL / 128), blk, 0, stream>>>(
      AO, DMODEL, W_eproj, DMODEL, L_TXT, DMODEL, DMODEL,
      out + (size_t)L_IMG * DMODEL, nullptr, nullptr, b_eproj, 0);
}

// Round 6
// 1297.827 us; speedup vs baseline: 1.2914x; 1.2914x over previous
//
#include <hip/hip_runtime.h>
#include <hip/hip_bf16.h>
#include <cstdint>

typedef __attribute__((ext_vector_type(8))) short u16x8;
typedef _Float16 f16_t;
typedef __attribute__((ext_vector_type(8))) f16_t f16x8;
typedef __attribute__((ext_vector_type(4))) float f32x4;

#define L_TOT 4608
#define L_TXT 512
#define L_IMG 4096
#define NH 24
#define HD 128
#define DMODEL 3072
#define NQKV 9216
#define LOG2E 1.44269504088896340736f
#define S_SHIFT 32.0f

__device__ __forceinline__ ushort f2h(float f) {
  union { f16_t h; ushort u; } c; c.h = (f16_t)f; return c.u;
}
__device__ __forceinline__ float h2f(ushort u) {
  union { ushort u; f16_t h; } c; c.u = u; return (float)c.h;
}
__device__ __forceinline__ void gload16(const ushort* g, ushort* l) {
  __builtin_amdgcn_global_load_lds((const __attribute__((address_space(1))) void*)g,
                                   (__attribute__((address_space(3))) void*)l, 16, 0, 0);
}

// ------- tconv_w: f32 weight [3072][C], col-slice c0..c0+Nsl -> fp16 [Nsl][3072] --------
__global__ void tconv_w(const float* __restrict__ src, int C, int c0,
                        ushort* __restrict__ dst) {
  __shared__ ushort tile[64][72];
  const int nb = blockIdx.x << 6, kb = blockIdx.y << 6;
  const int t = threadIdx.x;
  const int lr = t >> 2, lc = (t & 3) << 4;
  const float* sp = src + (size_t)(kb + lr) * C + c0 + nb + lc;
  const f32x4 v0 = *(const f32x4*)sp;
  const f32x4 v1 = *(const f32x4*)(sp + 4);
  const f32x4 v2 = *(const f32x4*)(sp + 8);
  const f32x4 v3 = *(const f32x4*)(sp + 12);
#pragma unroll
  for (int i = 0; i < 4; ++i) {
    tile[lr][lc + i]      = f2h(v0[i]);
    tile[lr][lc + 4 + i]  = f2h(v1[i]);
    tile[lr][lc + 8 + i]  = f2h(v2[i]);
    tile[lr][lc + 12 + i] = f2h(v3[i]);
  }
  __syncthreads();
  const int cl = t & 63, rb = (t >> 6) << 4;
  alignas(16) ushort o[16];
#pragma unroll
  for (int i = 0; i < 16; ++i) o[i] = tile[rb + i][cl];
  ushort* dp = dst + (size_t)(nb + cl) * DMODEL + kb + rb;
  *(u16x8*)dp       = *(const u16x8*)o;
  *(u16x8*)(dp + 8) = *(const u16x8*)(o + 8);
}

// ------- tconv_h: fp16 src [R][C] -> dst [C][R] (for V -> V^T) --------------------------
__global__ void tconv_h(const ushort* __restrict__ src, ushort* __restrict__ dst,
                        int R, int C) {
  __shared__ ushort tile[64][72];
  const int r0 = blockIdx.y << 6, c0 = blockIdx.x << 6;
  const int t = threadIdx.x;
  const int lr = t >> 2, lc = (t & 3) << 4;
  const ushort* sp = src + (size_t)(r0 + lr) * C + c0 + lc;
  const u16x8 v0 = *(const u16x8*)sp;
  const u16x8 v1 = *(const u16x8*)(sp + 8);
#pragma unroll
  for (int i = 0; i < 8; ++i) {
    tile[lr][lc + i]     = ((const ushort*)&v0)[i];
    tile[lr][lc + 8 + i] = ((const ushort*)&v1)[i];
  }
  __syncthreads();
  const int cl = t & 63, rb = (t >> 6) << 4;
  alignas(16) ushort o[16];
#pragma unroll
  for (int i = 0; i < 16; ++i) o[i] = tile[rb + i][cl];
  ushort* dp = dst + (size_t)(c0 + cl) * R + r0 + rb;
  *(u16x8*)dp       = *(const u16x8*)o;
  *(u16x8*)(dp + 8) = *(const u16x8*)(o + 8);
}

// ---------------- GEMM: C[M][N] = A[M][K] @ Bt[N][K]^T, 128x128 tile, BK=32 ------------
// ASRC: 0 = A fp16 [M][K] via global_load_lds ; 1 = A f32 [M][K] via reg-stage + cvt
// B: always fp16 [N][K] via global_load_lds
// MODE: 0 = qkv scatter fp16 into merged Q/K/V [l][3072] (l = l_off + m,
//           global n = n_base + n0 + local; which = n/3072, col = n%3072)
//       1 = f32 out + f32 bias ; 2 = plain fp16 out ; 3 = fp16 out, minus S_SHIFT
template <int MODE, int ASRC>
__global__ void gemm(const void* __restrict__ Av, int lda,
                     const ushort* __restrict__ Bt, int ldb,
                     int M, int N, int K,
                     void* __restrict__ out0, ushort* __restrict__ out1,
                     ushort* __restrict__ out2, const float* __restrict__ bias,
                     int l_off, int n_base) {
  __shared__ __align__(16) ushort Alds[128 * 32];
  __shared__ __align__(16) ushort Blds[128 * 32];
  const int m0 = blockIdx.x << 7, n0 = blockIdx.y << 7;
  const int tid = threadIdx.x, wave = tid >> 6, lane = tid & 63;
  const int wr = wave >> 1, wc = wave & 1;
  const int lrow = lane & 15, lk8 = (lane >> 4) << 3;
  f32x4 acc[4][4];
#pragma unroll
  for (int a = 0; a < 4; ++a)
#pragma unroll
    for (int b = 0; b < 4; ++b) acc[a][b] = (f32x4){0.f, 0.f, 0.f, 0.f};
  const int nk = K >> 5;

  const ushort* Ap = nullptr; const float* Apf = nullptr;
  int arow_f = 0, ao_f = 0;
  if (ASRC == 0) {
    Ap = (const ushort*)Av + (size_t)(m0 + (tid >> 2)) * lda + ((tid & 3) << 3);
  } else {
    arow_f = tid >> 1; ao_f = (tid & 1) << 4;
    Apf = (const float*)Av + (size_t)(m0 + arow_f) * lda + ao_f;
  }
  const ushort* Bp = Bt + (size_t)(n0 + (tid >> 2)) * ldb + ((tid & 3) << 3);

  for (int ks = 0; ks < nk; ++ks) {
    f32x4 a4[4];
    if (ASRC == 1) {
      const float* as = Apf + (ks << 5);
      a4[0] = *(const f32x4*)as;       a4[1] = *(const f32x4*)(as + 4);
      a4[2] = *(const f32x4*)(as + 8); a4[3] = *(const f32x4*)(as + 12);
    }
    __syncthreads();  // previous iteration's LDS readers done
    if (ASRC == 0) {
      const ushort* a0 = Ap + (ks << 5);
      gload16(a0, &Alds[wave << 9]);
      gload16(a0 + (size_t)64 * lda, &Alds[2048 + (wave << 9)]);
    } else {
      alignas(16) ushort ac[16];
      const float* af_ = (const float*)a4;
#pragma unroll
      for (int i = 0; i < 16; ++i) ac[i] = f2h(af_[i]);
      *(u16x8*)&Alds[arow_f * 32 + ao_f]     = *(const u16x8*)ac;
      *(u16x8*)&Alds[arow_f * 32 + ao_f + 8] = *(const u16x8*)(ac + 8);
    }
    {
      const ushort* b0 = Bp + (ks << 5);
      gload16(b0, &Blds[wave << 9]);
      gload16(b0 + (size_t)64 * ldb, &Blds[2048 + (wave << 9)]);
    }
    __syncthreads();  // tiles ready
    f16x8 af[4], bfr[4];
#pragma unroll
    for (int mt = 0; mt < 4; ++mt)
      af[mt] = *(const f16x8*)&Alds[((wr << 6) + (mt << 4) + lrow) * 32 + lk8];
#pragma unroll
    for (int nt = 0; nt < 4; ++nt)
      bfr[nt] = *(const f16x8*)&Blds[((wc << 6) + (nt << 4) + lrow) * 32 + lk8];
#pragma unroll
    for (int mt = 0; mt < 4; ++mt)
#pragma unroll
      for (int nt = 0; nt < 4; ++nt)
        acc[mt][nt] = __builtin_amdgcn_mfma_f32_16x16x32_f16(af[mt], bfr[nt], acc[mt][nt], 0, 0, 0);
  }
  const int rb = (lane >> 4) << 2;
  if (MODE == 0) {
    const int g = n_base + n0;
    const int which = g / DMODEL;
    const int col0 = g - which * DMODEL;
    ushort* dst = (which == 0) ? (ushort*)out0 : (which == 1) ? out1 : out2;
#pragma unroll
    for (int mt = 0; mt < 4; ++mt)
#pragma unroll
      for (int j = 0; j < 4; ++j) {
        const int l = l_off + m0 + (wr << 6) + (mt << 4) + rb + j;
        const size_t rbase = (size_t)l * DMODEL + col0 + (wc << 6) + lrow;
#pragma unroll
        for (int nt = 0; nt < 4; ++nt) dst[rbase + (nt << 4)] = f2h(acc[mt][nt][j]);
      }
  } else if (MODE == 1) {
    float* outf = (float*)out0;
    float bv[4];
#pragma unroll
    for (int nt = 0; nt < 4; ++nt) bv[nt] = bias[n0 + (wc << 6) + (nt << 4) + lrow];
#pragma unroll
    for (int mt = 0; mt < 4; ++mt)
#pragma unroll
      for (int j = 0; j < 4; ++j) {
        const int r = m0 + (wr << 6) + (mt << 4) + rb + j;
        const size_t rbase = (size_t)r * N + n0 + (wc << 6) + lrow;
#pragma unroll
        for (int nt = 0; nt < 4; ++nt) outf[rbase + (nt << 4)] = acc[mt][nt][j] + bv[nt];
      }
  } else {
    ushort* outb = (ushort*)out0;
    const float sh = (MODE == 3) ? S_SHIFT : 0.0f;
#pragma unroll
    for (int mt = 0; mt < 4; ++mt)
#pragma unroll
      for (int j = 0; j < 4; ++j) {
        const int r = m0 + (wr << 6) + (mt << 4) + rb + j;
        const size_t rbase = (size_t)r * N + n0 + (wc << 6) + lrow;
#pragma unroll
        for (int nt = 0; nt < 4; ++nt) outb[rbase + (nt << 4)] = f2h(acc[mt][nt][j] - sh);
      }
  }
}

// ---------------- fused RMSNorm + RoPE on merged Q,K [l][3072] fp16; f32 params --------
__global__ void norm_rope(ushort* __restrict__ Q, ushort* __restrict__ Kg,
                          const float* __restrict__ rope,
                          const float* __restrict__ qn, const float* __restrict__ kn,
                          const float* __restrict__ eqn, const float* __restrict__ ekn) {
  const int idx = (blockIdx.x << 2) + (threadIdx.x >> 6);  // (l*24 + h)
  const int lane = threadIdx.x & 63;
  const int h = idx % NH, l = idx / NH;
  const float* qsc = (l < L_TXT) ? eqn : qn;
  const float* ksc = (l < L_TXT) ? ekn : kn;
  const size_t base = (size_t)l * DMODEL + h * HD + (lane << 1);
  const f32x4 fcv = *(const f32x4*)(rope + ((size_t)l * 64 + lane) * 4);
  const float fa = fcv[0], fb = fcv[1], fc = fcv[2], fd = fcv[3];
  const float s0 = qsc[lane << 1], s1 = qsc[(lane << 1) + 1];
  const float t0 = ksc[lane << 1], t1 = ksc[(lane << 1) + 1];
  {
    const uint32_t qv = *(const uint32_t*)&Q[base];
    float x0 = h2f((ushort)(qv & 0xffff)), x1 = h2f((ushort)(qv >> 16));
    float ss = x0 * x0 + x1 * x1;
#pragma unroll
    for (int m = 1; m < 64; m <<= 1) ss += __shfl_xor(ss, m);
    const float r = rsqrtf(ss * (1.0f / 128.0f) + 1e-6f);
    x0 *= r * s0;
    x1 *= r * s1;
    const float o0 = (fa * x0 + fb * x1) * 0.08838834764831845f;
    const float o1 = (fc * x0 + fd * x1) * 0.08838834764831845f;
    *(uint32_t*)&Q[base] = (uint32_t)f2h(o0) | ((uint32_t)f2h(o1) << 16);
  }
  {
    const uint32_t kv = *(const uint32_t*)&Kg[base];
    float x0 = h2f((ushort)(kv & 0xffff)), x1 = h2f((ushort)(kv >> 16));
    float ss = x0 * x0 + x1 * x1;
#pragma unroll
    for (int m = 1; m < 64; m <<= 1) ss += __shfl_xor(ss, m);
    const float r = rsqrtf(ss * (1.0f / 128.0f) + 1e-6f);
    x0 *= r * t0;
    x1 *= r * t1;
    const float o0 = fa * x0 + fb * x1;
    const float o1 = fc * x0 + fd * x1;
    *(uint32_t*)&Kg[base] = (uint32_t)f2h(o0) | ((uint32_t)f2h(o1) << 16);
  }
}

// ---------------- row softmax in-place on fp16 S[4608][4608] ---------------------------
__global__ void softmax_rows(ushort* __restrict__ S) {
  const int r = blockIdx.x, tid = threadIdx.x;
  ushort* Sr = S + (size_t)r * L_TOT;
  float v[18];
  float m = -3.0e38f;
#pragma unroll
  for (int j = 0; j < 18; ++j) { v[j] = h2f(Sr[tid + (j << 8)]); m = fmaxf(m, v[j]); }
#pragma unroll
  for (int o = 1; o < 64; o <<= 1) m = fmaxf(m, __shfl_xor(m, o));
  __shared__ float redm[4], reds[4];
  const int wave = tid >> 6, lane = tid & 63;
  if (lane == 0) redm[wave] = m;
  __syncthreads();
  m = fmaxf(fmaxf(redm[0], redm[1]), fmaxf(redm[2], redm[3]));
  float s = 0.f;
#pragma unroll
  for (int j = 0; j < 18; ++j) { v[j] = exp2f((v[j] - m) * LOG2E); s += v[j]; }
#pragma unroll
  for (int o = 1; o < 64; o <<= 1) s += __shfl_xor(s, o);
  if (lane == 0) reds[wave] = s;
  __syncthreads();
  const float inv = 1.0f / (reds[0] + reds[1] + reds[2] + reds[3]);
#pragma unroll
  for (int j = 0; j < 18; ++j) Sr[tid + (j << 8)] = f2h(v[j] * inv);
}

extern "C" void kernel_launch(void* const* d_in, const int* in_sizes, int n_in,
                              void* d_out, int out_size, void* d_ws, size_t ws_size,
                              hipStream_t stream) {
  (void)in_sizes; (void)n_in; (void)out_size; (void)ws_size;
  const float* hidden  = (const float*)d_in[0];
  const float* enc     = (const float*)d_in[1];
  const float* rope    = (const float*)d_in[2];
  const float* W_iqkv  = (const float*)d_in[3];
  const float* W_eqkv  = (const float*)d_in[4];
  const float* W_iproj = (const float*)d_in[5];
  const float* b_iproj = (const float*)d_in[6];
  const float* W_eproj = (const float*)d_in[7];
  const float* b_eproj = (const float*)d_in[8];
  const float* qn  = (const float*)d_in[9];
  const float* kn  = (const float*)d_in[10];
  const float* eqn = (const float*)d_in[11];
  const float* ekn = (const float*)d_in[12];
  float* out = (float*)d_out;

  // ws (ushort units), 127.4 MB total — proven footprint.
  // R0 (4608*4608): WT halves (28.3MB) -> S (42.5MB)
  // QR (->AO), KR (->VT), VR (->proj WT)
  const size_t SZ_S  = (size_t)L_TOT * L_TOT;
  const size_t SZ_LD = (size_t)L_TOT * DMODEL;
  ushort* R0 = (ushort*)d_ws;
  ushort* WT = R0;
  ushort* S  = R0;
  ushort* QR = R0 + SZ_S;
  ushort* KR = QR + SZ_LD;
  ushort* VR = KR + SZ_LD;
  ushort* VT = KR;   // alias: KR dead after S GEMM
  ushort* AO = QR;   // alias: QR dead after S GEMM
  ushort* WP = VR;   // alias: VR dead after V-transpose

  dim3 blk(256);
  const dim3 gW(72, 48), gP(48, 48);
  // QKV projections, N split in two 4608-col halves (WT buffer reused)
  for (int h = 0; h < 2; ++h) {
    tconv_w<<<gW, blk, 0, stream>>>(W_iqkv, NQKV, h * 4608, WT);
    gemm<0, 1><<<dim3(L_IMG / 128, 36), blk, 0, stream>>>(
        hidden, DMODEL, WT, DMODEL, L_IMG, 4608, DMODEL, QR, KR, VR, nullptr,
        L_TXT, h * 4608);
    tconv_w<<<gW, blk, 0, stream>>>(W_eqkv, NQKV, h * 4608, WT);
    gemm<0, 1><<<dim3(L_TXT / 128, 36), blk, 0, stream>>>(
        enc, DMODEL, WT, DMODEL, L_TXT, 4608, DMODEL, QR, KR, VR, nullptr,
        0, h * 4608);
  }
  // per-head RMSNorm + RoPE (attn scale folded into Q)
  norm_rope<<<dim3(L_TOT * NH / 4), blk, 0, stream>>>(QR, KR, rope, qn, kn, eqn, ekn);
  // S = Q K^T - 32 (fp16)
  gemm<3, 0><<<dim3(L_TOT / 128, L_TOT / 128), blk, 0, stream>>>(
      QR, DMODEL, KR, DMODEL, L_TOT, L_TOT, DMODEL, S, nullptr, nullptr, nullptr, 0, 0);
  // row softmax in place
  softmax_rows<<<dim3(L_TOT), blk, 0, stream>>>(S);
  // V^T (fp16 [3072][4608]) for the PV GEMM
  tconv_h<<<dim3(48, 72), blk, 0, stream>>>(VR, VT, L_TOT, DMODEL);
  // AO = P @ V
  gemm<2, 0><<<dim3(L_TOT / 128, DMODEL / 128), blk, 0, stream>>>(
      S, L_TOT, VT, L_TOT, L_TOT, DMODEL, L_TOT, AO, nullptr, nullptr, nullptr, 0, 0);
  // output projections
  tconv_w<<<gP, blk, 0, stream>>>(W_iproj, DMODEL, 0, WP);
  gemm<1, 0><<<dim3(L_IMG / 128, DMODEL / 128), blk, 0, stream>>>(
      AO + (size_t)L_TXT * DMODEL, DMODEL, WP, DMODEL, L_IMG, DMODEL, DMODEL,
      out, nullptr, nullptr, b_iproj, 0, 0);
  tconv_w<<<gP, blk, 0, stream>>>(W_eproj, DMODEL, 0, WP);
  gemm<1, 0><<<dim3(L_TXT / 128, DMODEL / 128), blk, 0, stream>>>(
      AO, DMODEL, WP, DMODEL, L_TXT, DMODEL, DMODEL,
      out + (size_t)L_IMG * DMODEL, nullptr, nullptr, b_eproj, 0, 0);
}

// Round 7
// 1274.467 us; speedup vs baseline: 1.3151x; 1.0183x over previous
//
#include <hip/hip_runtime.h>
#include <hip/hip_bf16.h>
#include <cstdint>

typedef __attribute__((ext_vector_type(8))) short u16x8;
typedef _Float16 f16_t;
typedef __attribute__((ext_vector_type(8))) f16_t f16x8;
typedef __attribute__((ext_vector_type(4))) float f32x4;

#define L_TOT 4608
#define L_TXT 512
#define L_IMG 4096
#define NH 24
#define HD 128
#define DMODEL 3072
#define NQKV 9216
#define LOG2E 1.44269504088896340736f
#define S_SHIFT 32.0f

__device__ __forceinline__ ushort f2h(float f) {
  union { f16_t h; ushort u; } c; c.h = (f16_t)f; return c.u;
}
__device__ __forceinline__ float h2f(ushort u) {
  union { ushort u; f16_t h; } c; c.u = u; return (float)c.h;
}
__device__ __forceinline__ void gload16(const ushort* g, ushort* l) {
  __builtin_amdgcn_global_load_lds((const __attribute__((address_space(1))) void*)g,
                                   (__attribute__((address_space(3))) void*)l, 16, 0, 0);
}

// ------- cvt_f32_f16: elementwise f32 -> fp16, 8 elems/thread ---------------------------
__global__ void cvt_f32_f16(const float* __restrict__ src, ushort* __restrict__ dst,
                            int n8) {
  const int i = blockIdx.x * 256 + threadIdx.x;
  if (i >= n8) return;
  const f32x4 a = *(const f32x4*)(src + (size_t)i * 8);
  const f32x4 b = *(const f32x4*)(src + (size_t)i * 8 + 4);
  alignas(16) ushort o[8];
#pragma unroll
  for (int j = 0; j < 4; ++j) { o[j] = f2h(a[j]); o[4 + j] = f2h(b[j]); }
  *(u16x8*)(dst + (size_t)i * 8) = *(const u16x8*)o;
}

// ------- tconv_w: f32 weight [3072][C], col-slice c0..c0+Nsl -> fp16 [Nsl][3072] --------
__global__ void tconv_w(const float* __restrict__ src, int C, int c0,
                        ushort* __restrict__ dst) {
  __shared__ ushort tile[64][72];
  const int nb = blockIdx.x << 6, kb = blockIdx.y << 6;
  const int t = threadIdx.x;
  const int lr = t >> 2, lc = (t & 3) << 4;
  const float* sp = src + (size_t)(kb + lr) * C + c0 + nb + lc;
  const f32x4 v0 = *(const f32x4*)sp;
  const f32x4 v1 = *(const f32x4*)(sp + 4);
  const f32x4 v2 = *(const f32x4*)(sp + 8);
  const f32x4 v3 = *(const f32x4*)(sp + 12);
#pragma unroll
  for (int i = 0; i < 4; ++i) {
    tile[lr][lc + i]      = f2h(v0[i]);
    tile[lr][lc + 4 + i]  = f2h(v1[i]);
    tile[lr][lc + 8 + i]  = f2h(v2[i]);
    tile[lr][lc + 12 + i] = f2h(v3[i]);
  }
  __syncthreads();
  const int cl = t & 63, rb = (t >> 6) << 4;
  alignas(16) ushort o[16];
#pragma unroll
  for (int i = 0; i < 16; ++i) o[i] = tile[rb + i][cl];
  ushort* dp = dst + (size_t)(nb + cl) * DMODEL + kb + rb;
  *(u16x8*)dp       = *(const u16x8*)o;
  *(u16x8*)(dp + 8) = *(const u16x8*)(o + 8);
}

// ------- tconv_h: fp16 src [R][C] -> dst [C][R] (for V -> V^T) --------------------------
__global__ void tconv_h(const ushort* __restrict__ src, ushort* __restrict__ dst,
                        int R, int C) {
  __shared__ ushort tile[64][72];
  const int r0 = blockIdx.y << 6, c0 = blockIdx.x << 6;
  const int t = threadIdx.x;
  const int lr = t >> 2, lc = (t & 3) << 4;
  const ushort* sp = src + (size_t)(r0 + lr) * C + c0 + lc;
  const u16x8 v0 = *(const u16x8*)sp;
  const u16x8 v1 = *(const u16x8*)(sp + 8);
#pragma unroll
  for (int i = 0; i < 8; ++i) {
    tile[lr][lc + i]     = ((const ushort*)&v0)[i];
    tile[lr][lc + 8 + i] = ((const ushort*)&v1)[i];
  }
  __syncthreads();
  const int cl = t & 63, rb = (t >> 6) << 4;
  alignas(16) ushort o[16];
#pragma unroll
  for (int i = 0; i < 16; ++i) o[i] = tile[rb + i][cl];
  ushort* dp = dst + (size_t)(c0 + cl) * R + r0 + rb;
  *(u16x8*)dp       = *(const u16x8*)o;
  *(u16x8*)(dp + 8) = *(const u16x8*)(o + 8);
}

// ---------------- GEMM: C[M][N] = A[M][K] @ Bt[N][K]^T, 128x128 tile, BK=32 ------------
// A fp16 [M][K], B fp16 [N][K], both staged via global_load_lds (m97 structure)
// MODE: 0 = qkv scatter fp16 into merged Q/K/V [l][3072] (l = l_off + m,
//           global n = n_base + n0 + local; which = n/3072, col = n%3072)
//       1 = f32 out + f32 bias ; 2 = plain fp16 out ; 3 = fp16 out, minus S_SHIFT
template <int MODE>
__global__ void gemm(const ushort* __restrict__ A, int lda,
                     const ushort* __restrict__ Bt, int ldb,
                     int M, int N, int K,
                     void* __restrict__ out0, ushort* __restrict__ out1,
                     ushort* __restrict__ out2, const float* __restrict__ bias,
                     int l_off, int n_base) {
  __shared__ __align__(16) ushort Alds[128 * 32];
  __shared__ __align__(16) ushort Blds[128 * 32];
  const int m0 = blockIdx.x << 7, n0 = blockIdx.y << 7;
  const int tid = threadIdx.x, wave = tid >> 6, lane = tid & 63;
  const int wr = wave >> 1, wc = wave & 1;
  const int lrow = lane & 15, lk8 = (lane >> 4) << 3;
  f32x4 acc[4][4];
#pragma unroll
  for (int a = 0; a < 4; ++a)
#pragma unroll
    for (int b = 0; b < 4; ++b) acc[a][b] = (f32x4){0.f, 0.f, 0.f, 0.f};
  const int nk = K >> 5;
  const ushort* Ap = A + (size_t)(m0 + (tid >> 2)) * lda + ((tid & 3) << 3);
  const ushort* Bp = Bt + (size_t)(n0 + (tid >> 2)) * ldb + ((tid & 3) << 3);

  for (int ks = 0; ks < nk; ++ks) {
    __syncthreads();  // previous iteration's LDS readers done
    {
      const ushort* a0 = Ap + (ks << 5);
      gload16(a0, &Alds[wave << 9]);
      gload16(a0 + (size_t)64 * lda, &Alds[2048 + (wave << 9)]);
      const ushort* b0 = Bp + (ks << 5);
      gload16(b0, &Blds[wave << 9]);
      gload16(b0 + (size_t)64 * ldb, &Blds[2048 + (wave << 9)]);
    }
    __syncthreads();  // tiles ready (vmcnt(0) drained before barrier)
    f16x8 af[4], bfr[4];
#pragma unroll
    for (int mt = 0; mt < 4; ++mt)
      af[mt] = *(const f16x8*)&Alds[((wr << 6) + (mt << 4) + lrow) * 32 + lk8];
#pragma unroll
    for (int nt = 0; nt < 4; ++nt)
      bfr[nt] = *(const f16x8*)&Blds[((wc << 6) + (nt << 4) + lrow) * 32 + lk8];
#pragma unroll
    for (int mt = 0; mt < 4; ++mt)
#pragma unroll
      for (int nt = 0; nt < 4; ++nt)
        acc[mt][nt] = __builtin_amdgcn_mfma_f32_16x16x32_f16(af[mt], bfr[nt], acc[mt][nt], 0, 0, 0);
  }
  const int rb = (lane >> 4) << 2;
  if (MODE == 0) {
    const int g = n_base + n0;
    const int which = g / DMODEL;
    const int col0 = g - which * DMODEL;
    ushort* dst = (which == 0) ? (ushort*)out0 : (which == 1) ? out1 : out2;
#pragma unroll
    for (int mt = 0; mt < 4; ++mt)
#pragma unroll
      for (int j = 0; j < 4; ++j) {
        const int l = l_off + m0 + (wr << 6) + (mt << 4) + rb + j;
        const size_t rbase = (size_t)l * DMODEL + col0 + (wc << 6) + lrow;
#pragma unroll
        for (int nt = 0; nt < 4; ++nt) dst[rbase + (nt << 4)] = f2h(acc[mt][nt][j]);
      }
  } else if (MODE == 1) {
    float* outf = (float*)out0;
    float bv[4];
#pragma unroll
    for (int nt = 0; nt < 4; ++nt) bv[nt] = bias[n0 + (wc << 6) + (nt << 4) + lrow];
#pragma unroll
    for (int mt = 0; mt < 4; ++mt)
#pragma unroll
      for (int j = 0; j < 4; ++j) {
        const int r = m0 + (wr << 6) + (mt << 4) + rb + j;
        const size_t rbase = (size_t)r * N + n0 + (wc << 6) + lrow;
#pragma unroll
        for (int nt = 0; nt < 4; ++nt) outf[rbase + (nt << 4)] = acc[mt][nt][j] + bv[nt];
      }
  } else {
    ushort* outb = (ushort*)out0;
    const float sh = (MODE == 3) ? S_SHIFT : 0.0f;
#pragma unroll
    for (int mt = 0; mt < 4; ++mt)
#pragma unroll
      for (int j = 0; j < 4; ++j) {
        const int r = m0 + (wr << 6) + (mt << 4) + rb + j;
        const size_t rbase = (size_t)r * N + n0 + (wc << 6) + lrow;
#pragma unroll
        for (int nt = 0; nt < 4; ++nt) outb[rbase + (nt << 4)] = f2h(acc[mt][nt][j] - sh);
      }
  }
}

// ---------------- fused RMSNorm + RoPE on merged Q,K [l][3072] fp16; f32 params --------
__global__ void norm_rope(ushort* __restrict__ Q, ushort* __restrict__ Kg,
                          const float* __restrict__ rope,
                          const float* __restrict__ qn, const float* __restrict__ kn,
                          const float* __restrict__ eqn, const float* __restrict__ ekn) {
  const int idx = (blockIdx.x << 2) + (threadIdx.x >> 6);  // (l*24 + h)
  const int lane = threadIdx.x & 63;
  const int h = idx % NH, l = idx / NH;
  const float* qsc = (l < L_TXT) ? eqn : qn;
  const float* ksc = (l < L_TXT) ? ekn : kn;
  const size_t base = (size_t)l * DMODEL + h * HD + (lane << 1);
  const f32x4 fcv = *(const f32x4*)(rope + ((size_t)l * 64 + lane) * 4);
  const float fa = fcv[0], fb = fcv[1], fc = fcv[2], fd = fcv[3];
  const float s0 = qsc[lane << 1], s1 = qsc[(lane << 1) + 1];
  const float t0 = ksc[lane << 1], t1 = ksc[(lane << 1) + 1];
  {
    const uint32_t qv = *(const uint32_t*)&Q[base];
    float x0 = h2f((ushort)(qv & 0xffff)), x1 = h2f((ushort)(qv >> 16));
    float ss = x0 * x0 + x1 * x1;
#pragma unroll
    for (int m = 1; m < 64; m <<= 1) ss += __shfl_xor(ss, m);
    const float r = rsqrtf(ss * (1.0f / 128.0f) + 1e-6f);
    x0 *= r * s0;
    x1 *= r * s1;
    const float o0 = (fa * x0 + fb * x1) * 0.08838834764831845f;
    const float o1 = (fc * x0 + fd * x1) * 0.08838834764831845f;
    *(uint32_t*)&Q[base] = (uint32_t)f2h(o0) | ((uint32_t)f2h(o1) << 16);
  }
  {
    const uint32_t kv = *(const uint32_t*)&Kg[base];
    float x0 = h2f((ushort)(kv & 0xffff)), x1 = h2f((ushort)(kv >> 16));
    float ss = x0 * x0 + x1 * x1;
#pragma unroll
    for (int m = 1; m < 64; m <<= 1) ss += __shfl_xor(ss, m);
    const float r = rsqrtf(ss * (1.0f / 128.0f) + 1e-6f);
    x0 *= r * t0;
    x1 *= r * t1;
    const float o0 = fa * x0 + fb * x1;
    const float o1 = fc * x0 + fd * x1;
    *(uint32_t*)&Kg[base] = (uint32_t)f2h(o0) | ((uint32_t)f2h(o1) << 16);
  }
}

// ---------------- row softmax in-place on fp16 S[4608][4608] ---------------------------
__global__ void softmax_rows(ushort* __restrict__ S) {
  const int r = blockIdx.x, tid = threadIdx.x;
  ushort* Sr = S + (size_t)r * L_TOT;
  float v[18];
  float m = -3.0e38f;
#pragma unroll
  for (int j = 0; j < 18; ++j) { v[j] = h2f(Sr[tid + (j << 8)]); m = fmaxf(m, v[j]); }
#pragma unroll
  for (int o = 1; o < 64; o <<= 1) m = fmaxf(m, __shfl_xor(m, o));
  __shared__ float redm[4], reds[4];
  const int wave = tid >> 6, lane = tid & 63;
  if (lane == 0) redm[wave] = m;
  __syncthreads();
  m = fmaxf(fmaxf(redm[0], redm[1]), fmaxf(redm[2], redm[3]));
  float s = 0.f;
#pragma unroll
  for (int j = 0; j < 18; ++j) { v[j] = exp2f((v[j] - m) * LOG2E); s += v[j]; }
#pragma unroll
  for (int o = 1; o < 64; o <<= 1) s += __shfl_xor(s, o);
  if (lane == 0) reds[wave] = s;
  __syncthreads();
  const float inv = 1.0f / (reds[0] + reds[1] + reds[2] + reds[3]);
#pragma unroll
  for (int j = 0; j < 18; ++j) Sr[tid + (j << 8)] = f2h(v[j] * inv);
}

extern "C" void kernel_launch(void* const* d_in, const int* in_sizes, int n_in,
                              void* d_out, int out_size, void* d_ws, size_t ws_size,
                              hipStream_t stream) {
  (void)in_sizes; (void)n_in; (void)out_size; (void)ws_size;
  const float* hidden  = (const float*)d_in[0];
  const float* enc     = (const float*)d_in[1];
  const float* rope    = (const float*)d_in[2];
  const float* W_iqkv  = (const float*)d_in[3];
  const float* W_eqkv  = (const float*)d_in[4];
  const float* W_iproj = (const float*)d_in[5];
  const float* b_iproj = (const float*)d_in[6];
  const float* W_eproj = (const float*)d_in[7];
  const float* b_eproj = (const float*)d_in[8];
  const float* qn  = (const float*)d_in[9];
  const float* kn  = (const float*)d_in[10];
  const float* eqn = (const float*)d_in[11];
  const float* ekn = (const float*)d_in[12];
  float* out = (float*)d_out;

  // ws (ushort units), 127.4 MB total — proven footprint.
  // R0 (4608*4608 = 21.23M ushorts): during QKV = HF (12.58M) + EF (1.57M) + WTQ (7.08M)
  //                                  afterwards = S
  // QR (->AO), KR (->VT), VR (->proj WT)
  const size_t SZ_S  = (size_t)L_TOT * L_TOT;
  const size_t SZ_LD = (size_t)L_TOT * DMODEL;
  ushort* R0  = (ushort*)d_ws;
  ushort* HF  = R0;                                   // hidden fp16 [4096][3072]
  ushort* EF  = R0 + (size_t)L_IMG * DMODEL;          // enc fp16 [512][3072]
  ushort* WTQ = EF + (size_t)L_TXT * DMODEL;          // weight quarter fp16 [2304][3072]
  ushort* S   = R0;
  ushort* QR  = R0 + SZ_S;
  ushort* KR  = QR + SZ_LD;
  ushort* VR  = KR + SZ_LD;
  ushort* VT  = KR;   // alias: KR dead after S GEMM
  ushort* AO  = QR;   // alias: QR dead after S GEMM
  ushort* WP  = VR;   // alias: VR dead after V-transpose

  dim3 blk(256);
  // inputs -> fp16
  cvt_f32_f16<<<dim3(L_IMG * DMODEL / 8 / 256), blk, 0, stream>>>(hidden, HF,
                                                                  L_IMG * DMODEL / 8);
  cvt_f32_f16<<<dim3(L_TXT * DMODEL / 8 / 256), blk, 0, stream>>>(enc, EF,
                                                                  L_TXT * DMODEL / 8);
  // QKV projections, N split in four 2304-col quarters (WTQ buffer reused)
  for (int q = 0; q < 4; ++q) {
    const int c0 = q * 2304;
    tconv_w<<<dim3(36, 48), blk, 0, stream>>>(W_iqkv, NQKV, c0, WTQ);
    gemm<0><<<dim3(L_IMG / 128, 18), blk, 0, stream>>>(
        HF, DMODEL, WTQ, DMODEL, L_IMG, 2304, DMODEL, QR, KR, VR, nullptr, L_TXT, c0);
    tconv_w<<<dim3(36, 48), blk, 0, stream>>>(W_eqkv, NQKV, c0, WTQ);
    gemm<0><<<dim3(L_TXT / 128, 18), blk, 0, stream>>>(
        EF, DMODEL, WTQ, DMODEL, L_TXT, 2304, DMODEL, QR, KR, VR, nullptr, 0, c0);
  }
  // per-head RMSNorm + RoPE (attn scale folded into Q)
  norm_rope<<<dim3(L_TOT * NH / 4), blk, 0, stream>>>(QR, KR, rope, qn, kn, eqn, ekn);
  // S = Q K^T - 32 (fp16)
  gemm<3><<<dim3(L_TOT / 128, L_TOT / 128), blk, 0, stream>>>(
      QR, DMODEL, KR, DMODEL, L_TOT, L_TOT, DMODEL, S, nullptr, nullptr, nullptr, 0, 0);
  // row softmax in place
  softmax_rows<<<dim3(L_TOT), blk, 0, stream>>>(S);
  // V^T (fp16 [3072][4608]) for the PV GEMM
  tconv_h<<<dim3(48, 72), blk, 0, stream>>>(VR, VT, L_TOT, DMODEL);
  // AO = P @ V
  gemm<2><<<dim3(L_TOT / 128, DMODEL / 128), blk, 0, stream>>>(
      S, L_TOT, VT, L_TOT, L_TOT, DMODEL, L_TOT, AO, nullptr, nullptr, nullptr, 0, 0);
  // output projections
  tconv_w<<<dim3(48, 48), blk, 0, stream>>>(W_iproj, DMODEL, 0, WP);
  gemm<1><<<dim3(L_IMG / 128, DMODEL / 128), blk, 0, stream>>>(
      AO + (size_t)L_TXT * DMODEL, DMODEL, WP, DMODEL, L_IMG, DMODEL, DMODEL,
      out, nullptr, nullptr, b_iproj, 0, 0);
  tconv_w<<<dim3(48, 48), blk, 0, stream>>>(W_eproj, DMODEL, 0, WP);
  gemm<1><<<dim3(L_TXT / 128, DMODEL / 128), blk, 0, stream>>>(
      AO, DMODEL, WP, DMODEL, L_TXT, DMODEL, DMODEL,
      out + (size_t)L_IMG * DMODEL, nullptr, nullptr, b_eproj, 0, 0);
}